// Round 1
// baseline (673.439 us; speedup 1.0000x reference)
//
#include <hip/hip_runtime.h>

#define INVALID_TOKEN_ID -1

// One block per token row: argmax over `vocab` fp32 logits.
// First-occurrence tie-break (matches jnp.argmax).
__global__ __launch_bounds__(256) void rowargmax_kernel(
    const float* __restrict__ logits, int* __restrict__ amax, int vocab) {
    const int row = blockIdx.x;
    const float* rowp = logits + (size_t)row * (size_t)vocab;

    float best = -__builtin_inff();
    int bestIdx = 0;

    const int nvec = vocab >> 2;  // float4 count
    const float4* rowv = (const float4*)rowp;
    // Each thread walks strictly increasing indices -> strict '>' keeps
    // the first occurrence within a thread.
    for (int i = threadIdx.x; i < nvec; i += 256) {
        float4 v = rowv[i];
        int base = i << 2;
        if (v.x > best) { best = v.x; bestIdx = base; }
        if (v.y > best) { best = v.y; bestIdx = base + 1; }
        if (v.z > best) { best = v.z; bestIdx = base + 2; }
        if (v.w > best) { best = v.w; bestIdx = base + 3; }
    }
    // scalar tail (vocab not divisible by 4)
    for (int i = (nvec << 2) + threadIdx.x; i < vocab; i += 256) {
        float v = rowp[i];
        if (v > best) { best = v; bestIdx = i; }
    }

    // wave (64-lane) butterfly reduction; ties -> lower index
    #pragma unroll
    for (int off = 32; off > 0; off >>= 1) {
        float ov = __shfl_down(best, off, 64);
        int oi = __shfl_down(bestIdx, off, 64);
        if (ov > best || (ov == best && oi < bestIdx)) { best = ov; bestIdx = oi; }
    }

    __shared__ float svals[4];
    __shared__ int sidx[4];
    const int wave = threadIdx.x >> 6;
    if ((threadIdx.x & 63) == 0) { svals[wave] = best; sidx[wave] = bestIdx; }
    __syncthreads();
    if (threadIdx.x == 0) {
        #pragma unroll
        for (int w = 1; w < 4; ++w) {
            if (svals[w] > best || (svals[w] == best && sidx[w] < bestIdx)) {
                best = svals[w]; bestIdx = sidx[w];
            }
        }
        amax[row] = bestIdx;
    }
}

// One thread per batch row: cumulative accept + bonus position.
__global__ void finalize_kernel(const int* __restrict__ amax,
                                const int* __restrict__ spec,
                                int* __restrict__ out, int B, int k) {
    int b = blockIdx.x * blockDim.x + threadIdx.x;
    if (b >= B) return;
    const int kp1 = k + 1;

    int outv[8];
    int gen[8];
    #pragma unroll
    for (int j = 0; j < 8; ++j) { outv[j] = 0; gen[j] = 0; }

    for (int j = 0; j < kp1; ++j) outv[j] = amax[b * kp1 + j];

    int acc = 1;
    int firstZero = k;  // if all k drafts accepted, bonus goes at position k
    for (int j = 0; j < k; ++j) {
        if (acc && outv[j] != spec[b * k + j]) { acc = 0; firstZero = j; }
        gen[j] = acc;
    }
    gen[k] = 0;
    gen[firstZero] = 1;  // first rejected / bonus position

    for (int j = 0; j < kp1; ++j)
        out[b * kp1 + j] = gen[j] ? outv[j] : INVALID_TOKEN_ID;
}

extern "C" void kernel_launch(void* const* d_in, const int* in_sizes, int n_in,
                              void* d_out, int out_size, void* d_ws, size_t ws_size,
                              hipStream_t stream) {
    const float* logits = (const float*)d_in[0];
    const int* spec = (const int*)d_in[1];
    int* out = (int*)d_out;

    // total tokens = out_size (= B*(k+1)); spec is B*k elements.
    const int total_tokens = out_size;                 // 1024
    const int vocab = in_sizes[0] / total_tokens;      // 128000
    const int B = out_size - in_sizes[1];              // B*(k+1) - B*k = B = 128
    const int k = in_sizes[1] / B;                     // 7

    int* amax = (int*)d_ws;  // total_tokens ints of scratch

    rowargmax_kernel<<<total_tokens, 256, 0, stream>>>(logits, amax, vocab);
    finalize_kernel<<<(B + 127) / 128, 128, 0, stream>>>(amax, spec, out, B, k);
}

// Round 2
// 668.079 us; speedup vs baseline: 1.0080x; 1.0080x over previous
//
#include <hip/hip_runtime.h>

#define INVALID_TOKEN_ID -1

__device__ __forceinline__ void upd4(float4 v, int base, float& best, int& bestIdx) {
    // strictly increasing indices within a stream -> '>' keeps first occurrence
    if (v.x > best) { best = v.x; bestIdx = base; }
    if (v.y > best) { best = v.y; bestIdx = base + 1; }
    if (v.z > best) { best = v.z; bestIdx = base + 2; }
    if (v.w > best) { best = v.w; bestIdx = base + 3; }
}

// One block (512 thr = 8 waves) per token row: argmax over `vocab` fp32 logits.
// 4 blocks/CU * 8 waves = 32 waves/CU (occupancy cap); 2 independent load
// streams per thread for ILP. First-occurrence tie-break (matches jnp.argmax).
__global__ __launch_bounds__(512, 8) void rowargmax_kernel(
    const float* __restrict__ logits, int* __restrict__ amax, int vocab) {
    const int row = blockIdx.x;
    const int t = threadIdx.x;
    const float* rowp = logits + (size_t)row * (size_t)vocab;

    const int nvec = vocab >> 2;  // float4 count
    const float4* rowv = (const float4*)rowp;

    float best0 = -__builtin_inff(); int idx0 = 0;
    float best1 = -__builtin_inff(); int idx1 = 0;

    int i = t;
    for (; i + 512 < nvec; i += 1024) {
        float4 a = rowv[i];
        float4 b = rowv[i + 512];
        upd4(a, i << 2, best0, idx0);
        upd4(b, (i + 512) << 2, best1, idx1);
    }
    if (i < nvec) {
        float4 a = rowv[i];
        upd4(a, i << 2, best0, idx0);
    }
    // merge the two streams (index tie-break -> first occurrence)
    if (best1 > best0 || (best1 == best0 && idx1 < idx0)) { best0 = best1; idx0 = idx1; }

    // scalar tail (vocab not divisible by 4); tail indices exceed vector ones
    for (int j = (nvec << 2) + t; j < vocab; j += 512) {
        float v = rowp[j];
        if (v > best0) { best0 = v; idx0 = j; }
    }

    // wave (64-lane) butterfly reduction; ties -> lower index
    #pragma unroll
    for (int off = 32; off > 0; off >>= 1) {
        float ov = __shfl_down(best0, off, 64);
        int oi = __shfl_down(idx0, off, 64);
        if (ov > best0 || (ov == best0 && oi < idx0)) { best0 = ov; idx0 = oi; }
    }

    __shared__ float svals[8];
    __shared__ int sidx[8];
    const int wave = t >> 6;
    if ((t & 63) == 0) { svals[wave] = best0; sidx[wave] = idx0; }
    __syncthreads();
    if (t == 0) {
        #pragma unroll
        for (int w = 1; w < 8; ++w) {
            if (svals[w] > best0 || (svals[w] == best0 && sidx[w] < idx0)) {
                best0 = svals[w]; idx0 = sidx[w];
            }
        }
        amax[row] = idx0;
    }
}

// One thread per batch row: cumulative accept + bonus position.
__global__ void finalize_kernel(const int* __restrict__ amax,
                                const int* __restrict__ spec,
                                int* __restrict__ out, int B, int k) {
    int b = blockIdx.x * blockDim.x + threadIdx.x;
    if (b >= B) return;
    const int kp1 = k + 1;

    int outv[8];
    int gen[8];
    #pragma unroll
    for (int j = 0; j < 8; ++j) { outv[j] = 0; gen[j] = 0; }

    for (int j = 0; j < kp1; ++j) outv[j] = amax[b * kp1 + j];

    int acc = 1;
    int firstZero = k;  // if all k drafts accepted, bonus at position k
    for (int j = 0; j < k; ++j) {
        if (acc && outv[j] != spec[b * k + j]) { acc = 0; firstZero = j; }
        gen[j] = acc;
    }
    gen[k] = 0;
    gen[firstZero] = 1;  // first rejected / bonus position

    for (int j = 0; j < kp1; ++j)
        out[b * kp1 + j] = gen[j] ? outv[j] : INVALID_TOKEN_ID;
}

extern "C" void kernel_launch(void* const* d_in, const int* in_sizes, int n_in,
                              void* d_out, int out_size, void* d_ws, size_t ws_size,
                              hipStream_t stream) {
    const float* logits = (const float*)d_in[0];
    const int* spec = (const int*)d_in[1];
    int* out = (int*)d_out;

    const int total_tokens = out_size;                 // B*(k+1) = 1024
    const int vocab = in_sizes[0] / total_tokens;      // 128000
    const int B = out_size - in_sizes[1];              // B*(k+1) - B*k = 128
    const int k = in_sizes[1] / B;                     // 7

    int* amax = (int*)d_ws;  // total_tokens ints of scratch

    rowargmax_kernel<<<total_tokens, 512, 0, stream>>>(logits, amax, vocab);
    finalize_kernel<<<(B + 127) / 128, 128, 0, stream>>>(amax, spec, out, B, k);
}